// Round 14
// baseline (462.470 us; speedup 1.0000x reference)
//
#include <hip/hip_runtime.h>

typedef unsigned short u16;
typedef unsigned int u32;
typedef unsigned long long u64;

#define GN 100000
#define GE 1600000
#define DCAP 64        // padded CSR capacity per node (Poisson(16); P(>64) ~ 1e-20)
#define NRANGE 196     // 512-node dst ranges
#define NBKT (NRANGE * 8)
#define BCAP 1536      // per-bucket capacity (mean ~1027, +16 sigma)

typedef __bf16 bf16x8 __attribute__((ext_vector_type(8)));
typedef float f32x4 __attribute__((ext_vector_type(4)));
typedef float f32x2 __attribute__((ext_vector_type(2)));
typedef u32 u32x4 __attribute__((ext_vector_type(4)));
typedef u32 u32x2 __attribute__((ext_vector_type(2)));

__device__ __forceinline__ float bl(u32 u){ return __uint_as_float(u << 16); }
__device__ __forceinline__ float bh(u32 u){ return __uint_as_float(u & 0xffff0000u); }
__device__ __forceinline__ float bfu(u16 v){ return __uint_as_float(((u32)v) << 16); }
__device__ __forceinline__ u16 f2bf(float f){
    u32 u = __float_as_uint(f);
    u32 r = (u + 0x7fffu + ((u >> 16) & 1u)) >> 16;
    return (u16)r;
}
__device__ __forceinline__ u32 pack2(float a, float b){
    return (u32)f2bf(a) | ((u32)f2bf(b) << 16);
}
// 4 floats -> 4 fp8 e4m3 (HW cvt, RNE)
__device__ __forceinline__ u32 pk8x4(float a, float b, float c, float d){
    u32 p = (u32)__builtin_amdgcn_cvt_pk_fp8_f32(a, b, 0, false);
    p = (u32)__builtin_amdgcn_cvt_pk_fp8_f32(c, d, p, true);
    return p;
}

// ---- init: zero cursor/colpart(3 layers)/bcur; detect dtypes ----
// flags[0]: 1 => edge_index int64; flags[1]: 1 => float tensors are f32
__global__ void __launch_bounds__(256) k_init(const int* ei, const u32* xraw,
                                              int* cursor, float* colpart, int* flags,
                                              int* bcur){
    int i = blockIdx.x * 256 + threadIdx.x;
    if (i < GN) cursor[i] = 0;
    if (i < NBKT) bcur[i] = 0;
    if (i < 6144) colpart[i] = 0.f;
    int t = threadIdx.x;
    if (blockIdx.x == 0){
        __shared__ int s_any[4];
        int v = 0;
        #pragma unroll
        for (int j = 0; j < 4; ++j){
            int k = t * 4 + j;                // k in [0,1024)
            v |= ei[2 * k * 1000 + 1];        // dword pos <= 2046001 < 3.2M
        }
        #pragma unroll
        for (int m = 1; m < 64; m <<= 1) v |= __shfl_xor(v, m);
        if ((t & 63) == 0) s_any[t >> 6] = v;
        __syncthreads();
        if (t == 0){
            int any = s_any[0] | s_any[1] | s_any[2] | s_any[3];
            flags[0] = (any == 0) ? 1 : 0;
        }
    }
    if (blockIdx.x == 1){
        __shared__ int s_cnt[4];
        // low u16 of each dword: bf16 of ~N(0,1) has exponent in [100,140];
        // f32 mantissa bits hit that window ~16% of the time.
        int cnt = 0;
        #pragma unroll
        for (int j = 0; j < 4; ++j){
            int idx = (t * 4 + j) * 6000 + 3;     // < 6.15M dwords, safe both ways
            u32 u = xraw[idx];
            int e = (u >> 7) & 0xFF;
            cnt += (e >= 100 && e <= 140) ? 1 : 0;
        }
        #pragma unroll
        for (int m = 1; m < 64; m <<= 1) cnt += __shfl_xor(cnt, m);
        if ((t & 63) == 0) s_cnt[t >> 6] = cnt;
        __syncthreads();
        if (t == 0){
            int tot = s_cnt[0] + s_cnt[1] + s_cnt[2] + s_cnt[3];
            flags[1] = (tot > 512) ? 0 : 1;
        }
    }
}

// ---- convert x -> internal bf16 + fp8 shadow copy for the gather ----
__global__ void __launch_bounds__(256) k_convx(const void* x, const int* flags,
                                               u16* xb, u32* h8){
    int gid = blockIdx.x * 256 + threadIdx.x;     // one 8-element chunk
    if (gid >= GN * 16) return;
    float f0,f1,f2,f3,f4,f5,f6,f7;
    if (flags[1]){
        const u32x4* xf = (const u32x4*)x;
        u32x4 a = __builtin_nontemporal_load(xf + gid * 2);
        u32x4 b = __builtin_nontemporal_load(xf + gid * 2 + 1);
        f0 = __uint_as_float(a.x); f1 = __uint_as_float(a.y);
        f2 = __uint_as_float(a.z); f3 = __uint_as_float(a.w);
        f4 = __uint_as_float(b.x); f5 = __uint_as_float(b.y);
        f6 = __uint_as_float(b.z); f7 = __uint_as_float(b.w);
    } else {
        u32x4 g = __builtin_nontemporal_load((const u32x4*)x + gid);
        f0 = bl(g.x); f1 = bh(g.x); f2 = bl(g.y); f3 = bh(g.y);
        f4 = bl(g.z); f5 = bh(g.z); f6 = bl(g.w); f7 = bh(g.w);
    }
    u32x4 o;
    o.x = pack2(f0, f1); o.y = pack2(f2, f3);
    o.z = pack2(f4, f5); o.w = pack2(f6, f7);
    ((u32x4*)xb)[gid] = o;
    u32x2 e = { pk8x4(f0, f1, f2, f3), pk8x4(f4, f5, f6, f7) };
    ((u32x2*)h8)[gid] = e;
}

// ---- bf16 h -> fp8 shadow copy (refresh h8 between layers; clean seq writes) ----
__global__ void __launch_bounds__(256) k_tofp8(const u16* h, u32* h8){
    int gid = blockIdx.x * 256 + threadIdx.x;     // one 8-element chunk
    if (gid >= GN * 16) return;
    u32x4 g = ((const u32x4*)h)[gid];
    u32x2 e = { pk8x4(bl(g.x), bh(g.x), bl(g.y), bh(g.y)),
                pk8x4(bl(g.z), bh(g.z), bl(g.w), bh(g.w)) };
    ((u32x2*)h8)[gid] = e;
}

// ---- convert params -> bf16 block; Wl/Wr regions in GRANULE layout ----
// granule j (8 u16) = W[k=(j>>7)*8 .. +7][c=j&127] (8 consecutive k, fixed col)
#define WOFF_WR    49152
#define WOFF_B     98304
#define WOFF_G     98688
#define WOFF_BE    99072
#define WOFF_WLO   99456
#define WOFF_WRO   99584
#define WOFF_BO    99712
#define WTOT       99713
__global__ void __launch_bounds__(256) k_convw(const void* Wl, const void* Wr, const void* b,
                                               const void* g, const void* be, const void* wlo,
                                               const void* wro, const void* bo,
                                               const int* flags, u16* wbuf, float* biasf){
    int i = blockIdx.x * 256 + threadIdx.x;
    if (i >= WTOT) return;
    const void* s; int k;
    if (i < WOFF_B){
        const void* src = (i < WOFF_WR) ? Wl : Wr;
        int r = (i < WOFF_WR) ? i : i - WOFF_WR;
        int layer = r >> 14, L = r & 16383;
        int kk = ((L >> 10) << 3) | (L & 7);
        int cc = (L >> 3) & 127;
        int si = layer * 16384 + kk * 128 + cc;
        float fv = flags[1] ? ((const float*)src)[si] : bfu(((const u16*)src)[si]);
        wbuf[i] = f2bf(fv);
        return;
    }
    if      (i < WOFF_G  ){ s = b;   k = i - WOFF_B; }
    else if (i < WOFF_BE ){ s = g;   k = i - WOFF_G; }
    else if (i < WOFF_WLO){ s = be;  k = i - WOFF_BE; }
    else if (i < WOFF_WRO){ s = wlo; k = i - WOFF_WLO; }
    else if (i < WOFF_BO ){ s = wro; k = i - WOFF_WRO; }
    else                  { s = bo;  k = 0; }
    float fv = flags[1] ? ((const float*)s)[k] : bfu(((const u16*)s)[k]);
    wbuf[i] = f2bf(fv);
    if (i >= WOFF_B && i < WOFF_B + 384) biasf[i - WOFF_B] = fv;
}

// ---- pass A: LDS-staged radix scatter; wave-level shfl scan (5 barriers) ----
__global__ void __launch_bounds__(256) k_fillA(const int* ei, const int* flags,
                                               int* bcur, u64* pairs){
    __shared__ int cnt[256];
    __shared__ int lofs[256];
    __shared__ int gbase[NRANGE];
    __shared__ int wsum[4];
    __shared__ u64 lp[1024];
    int t = threadIdx.x;
    int lane = t & 63, w = t >> 6;
    int res = blockIdx.x & 7;
    int base = blockIdx.x * 1024;
    int is64 = flags[0];
    cnt[t] = 0;
    __syncthreads();
    int myd[4], mys[4], slot[4], myr[4];
    #pragma unroll
    for (int j = 0; j < 4; ++j){
        int e = base + j * 256 + t;
        if (e < GE){
            int d, s;
            if (is64){ d = __builtin_nontemporal_load(ei + 2 * (GE + e));
                       s = __builtin_nontemporal_load(ei + 2 * e); }
            else     { d = __builtin_nontemporal_load(ei + GE + e);
                       s = __builtin_nontemporal_load(ei + e); }
            myd[j] = d; mys[j] = s; myr[j] = d >> 9;
            slot[j] = atomicAdd(&cnt[myr[j]], 1);
        } else myr[j] = -1;
    }
    __syncthreads();
    int v = cnt[t];
    int sv = v;
    #pragma unroll
    for (int d = 1; d < 64; d <<= 1){
        int u = __shfl_up(sv, d);
        if (lane >= d) sv += u;
    }
    if (lane == 63) wsum[w] = sv;
    __syncthreads();
    int prefix = 0;
    #pragma unroll
    for (int j = 0; j < 4; ++j) if (j < w) prefix += wsum[j];
    lofs[t] = sv + prefix - v;                                  // exclusive
    if (t < NRANGE && cnt[t] > 0)
        gbase[t] = atomicAdd(&bcur[t * 8 + res], cnt[t]);
    __syncthreads();
    #pragma unroll
    for (int j = 0; j < 4; ++j){
        if (myr[j] >= 0)
            lp[lofs[myr[j]] + slot[j]] = ((u64)(u32)myd[j] << 32) | (u32)mys[j];
    }
    __syncthreads();
    int total = GE - base; if (total > 1024) total = 1024;
    for (int i = t; i < total; i += 256){
        u64 pr = lp[i];
        int r = (int)(pr >> 32) >> 9;
        int g = gbase[r] + (i - lofs[r]);
        if (g < BCAP) pairs[((size_t)(r * 8 + res)) * BCAP + g] = pr;
    }
}

// ---- pass B: scatter buckets into padded CSR (b%8 == range%8 => one XCD/window) ----
__global__ void __launch_bounds__(256) k_fillB(const int* bcur, const u64* pairs,
                                               int* cursor, int* col){
    int range = blockIdx.x % 200;
    int sub   = blockIdx.x / 200;
    if (range >= NRANGE || sub >= 8) return;
    int bkt = range * 8 + sub;
    int n = bcur[bkt]; if (n > BCAP) n = BCAP;
    const u64* P = pairs + (size_t)bkt * BCAP;
    for (int i = threadIdx.x; i < n; i += 256){
        u64 pr = __builtin_nontemporal_load(P + i);
        int s = (int)(u32)pr, d = (int)(pr >> 32);
        int pos = atomicAdd(&cursor[d], 1);
        if (pos < DCAP) col[d * DCAP + pos] = s;
    }
}

// ---- mean aggregation over the fp8 shadow: one wave (4 nodes), u32x2/lane,
// HW cvt decode, f32 accumulate, bf16 out. Row = 128 B = 2 cache lines.
__global__ void __launch_bounds__(64) k_agg(const u32* h8, const int* deg, const int* col,
                                            u16* amean){
    int lane = threadIdx.x;
    int grp = lane >> 4;                 // node within wave (0..3)
    int lg  = lane & 15;                 // 8B granule index within row
    int node = blockIdx.x * 4 + grp;
    if (node >= GN) return;
    int d = deg[node];
    int cnt = d < DCAP ? d : DCAP;
    const int* nb = col + node * DCAP;
    const u32x2* hrow = (const u32x2*)h8;      // 16 granules per 128-feat row
    float a0=0.f,a1=0.f,a2=0.f,a3=0.f,a4=0.f,a5=0.f,a6=0.f,a7=0.f;
    int e = 0;
    #define ACC8(v) { \
        f32x2 d0 = __builtin_amdgcn_cvt_pk_f32_fp8((v).x, false); \
        f32x2 d1 = __builtin_amdgcn_cvt_pk_f32_fp8((v).x, true);  \
        f32x2 d2 = __builtin_amdgcn_cvt_pk_f32_fp8((v).y, false); \
        f32x2 d3 = __builtin_amdgcn_cvt_pk_f32_fp8((v).y, true);  \
        a0 += d0.x; a1 += d0.y; a2 += d1.x; a3 += d1.y;           \
        a4 += d2.x; a5 += d2.y; a6 += d3.x; a7 += d3.y; }
    for (; e + 7 < cnt; e += 8){
        u32x2 v0 = hrow[(size_t)nb[e]     * 16 + lg];
        u32x2 v1 = hrow[(size_t)nb[e + 1] * 16 + lg];
        u32x2 v2 = hrow[(size_t)nb[e + 2] * 16 + lg];
        u32x2 v3 = hrow[(size_t)nb[e + 3] * 16 + lg];
        u32x2 v4 = hrow[(size_t)nb[e + 4] * 16 + lg];
        u32x2 v5 = hrow[(size_t)nb[e + 5] * 16 + lg];
        u32x2 v6 = hrow[(size_t)nb[e + 6] * 16 + lg];
        u32x2 v7 = hrow[(size_t)nb[e + 7] * 16 + lg];
        ACC8(v0) ACC8(v1) ACC8(v2) ACC8(v3) ACC8(v4) ACC8(v5) ACC8(v6) ACC8(v7)
    }
    for (; e + 1 < cnt; e += 2){
        u32x2 v0 = hrow[(size_t)nb[e]     * 16 + lg];
        u32x2 v1 = hrow[(size_t)nb[e + 1] * 16 + lg];
        ACC8(v0) ACC8(v1)
    }
    if (e < cnt){
        u32x2 v0 = hrow[(size_t)nb[e] * 16 + lg];
        ACC8(v0)
    }
    #undef ACC8
    float inv = (d > 0) ? 1.f / (float)d : 0.f;
    u32x4 o;
    o.x = pack2(a0 * inv, a1 * inv);
    o.y = pack2(a2 * inv, a3 * inv);
    o.z = pack2(a4 * inv, a5 * inv);
    o.w = pack2(a6 * inv, a7 * inv);
    ((u32x4*)amean)[(size_t)node * 16 + lg] = o;
}

// ---- BARRIER-FREE GEMM: hout = relu([amean|hin]@[Wl;Wr]+b).
// W is PRE-FOLDED (BN scale baked by k_bnf) in global granule layout and read
// per-fragment straight from L2 (64KB working set, hot in every XCD L2) —
// no LDS staging, no staging barriers, so all A-loads + W-loads issue freely
// and interleave with MFMA. LDS is only a 1KB stats buffer (occupancy is
// VGPR-bound). Epilogue keeps the clean column-per-lane store pattern.
__global__ void __launch_bounds__(256, 4) k_gemm(const u16* amean, const u16* hin,
                                                 const u16* Wlp, const u16* Wrp,
                                                 const float* biasf,
                                                 u16* hout, float* colpart){
    __shared__ float sst[256];        // sum[128], sumsq[128]
    int t = threadIdx.x;
    int wid = t >> 6, lane = t & 63;
    int quad = lane >> 4, l15 = lane & 15;
    int r0 = blockIdx.x * 128 + wid * 32;
    int node0 = r0 + l15, node1 = r0 + 16 + l15;
    sst[t] = 0.f;

    f32x4 acc[2][8];
    #pragma unroll
    for (int i = 0; i < 2; i++)
        #pragma unroll
        for (int j = 0; j < 8; j++) acc[i][j] = (f32x4){0.f, 0.f, 0.f, 0.f};

    #pragma unroll
    for (int half = 0; half < 2; ++half){
        const u16* A = half ? hin : amean;
        const u32x4* Wg = (const u32x4*)(half ? Wrp : Wlp);
        #pragma unroll
        for (int s = 0; s < 4; ++s){
            int kk = (s << 5) + (quad << 3);
            union { u32x4 u; bf16x8 v; } fa0, fa1;
            fa0.u = (node0 < GN) ? *(const u32x4*)(A + node0 * 128 + kk) : (u32x4){0,0,0,0};
            fa1.u = (node1 < GN) ? *(const u32x4*)(A + node1 * 128 + kk) : (u32x4){0,0,0,0};
            int kc = (s << 2) + quad;        // k-octet 0..15 within this half
            const u32x4* wg = Wg + (kc << 7) + l15;
            #pragma unroll
            for (int cb = 0; cb < 8; ++cb){
                union { u32x4 u; bf16x8 v; } fw;
                fw.u = wg[cb << 4];          // granule = kc*128 + cb*16 + l15
                acc[0][cb] = __builtin_amdgcn_mfma_f32_16x16x32_bf16(fa0.v, fw.v, acc[0][cb], 0, 0, 0);
                acc[1][cb] = __builtin_amdgcn_mfma_f32_16x16x32_bf16(fa1.v, fw.v, acc[1][cb], 0, 0, 0);
            }
        }
    }
    __syncthreads();                  // sst zero-init visible to all

    float bsv[8];
    #pragma unroll
    for (int cb = 0; cb < 8; cb++) bsv[cb] = biasf[cb * 16 + l15];

    #pragma unroll
    for (int cb = 0; cb < 8; cb++){
        float csum = 0.f, csq = 0.f;
        #pragma unroll
        for (int rb = 0; rb < 2; rb++){
            int rbase = r0 + rb * 16 + quad * 4;
            #pragma unroll
            for (int rr = 0; rr < 4; rr++){
                int row = rbase + rr;
                float v = acc[rb][cb][rr] + bsv[cb];
                v = fmaxf(v, 0.f);
                if (row < GN) hout[row * 128 + cb * 16 + l15] = f2bf(v);
                float vm = (row < GN) ? v : 0.f;
                csum += vm; csq += vm * vm;
            }
        }
        csum += __shfl_xor(csum, 16); csum += __shfl_xor(csum, 32);
        csq  += __shfl_xor(csq, 16);  csq  += __shfl_xor(csq, 32);
        if (quad == 0){
            atomicAdd(&sst[cb * 16 + l15], csum);
            atomicAdd(&sst[128 + cb * 16 + l15], csq);
        }
    }
    __syncthreads();
    atomicAdd(&colpart[(blockIdx.x & 7) * 256 + t], sst[t]);
}

// ---- BN finalize + fold: blocks 0..63 write next layer's scaled W (granule),
// block 64 folds bias (mode 0) or the output head (mode 1). ----
__global__ void __launch_bounds__(256) k_bnf(const float* colpart, const u16* gamma, const u16* beta,
                                             int mode,
                                             const u16* WlN, const u16* WrN, u16* wfd,
                                             const float* bNsrc, float* bNdst,
                                             const u16* wlo, const u16* wro, const u16* bo,
                                             u16* hwl, u16* hwr, float* hb){
    __shared__ float s_sc[128], s_sh[128], s_red[256];
    int t = threadIdx.x, b = blockIdx.x;
    if (t < 128){
        float s = 0.f, q = 0.f;
        #pragma unroll
        for (int j = 0; j < 8; ++j){
            s += colpart[j * 256 + t];
            q += colpart[j * 256 + 128 + t];
        }
        const float invn = 1.f / (float)GN;
        float mean = s * invn;
        float var = fmaxf(q * invn - mean * mean, 0.f);
        float rstd = rsqrtf(var + 1e-5f);
        float g  = bfu(gamma[t]);
        float be = bfu(beta[t]);
        float sc = g * rstd, sh = be - mean * sc;
        s_sc[t] = sc; s_sh[t] = sh;
    }
    __syncthreads();
    if (mode == 0){
        if (b < 64){
            int idx = b * 256 + t;            // granule index 0..16383
            int k = ((idx >> 10) << 3) | (idx & 7);
            float sc = s_sc[k];
            wfd[idx]         = f2bf(sc * bfu(WlN[idx]));
            wfd[16384 + idx] = f2bf(sc * bfu(WrN[idx]));
        } else if (t < 128){
            float acc = bNsrc[t];
            for (int k = 0; k < 128; ++k){
                int L = ((k >> 3) << 10) + (t << 3) + (k & 7);   // granule layout
                acc += s_sh[k] * (bfu(WlN[L]) + bfu(WrN[L]));
            }
            bNdst[t] = acc;
        }
    } else if (b == 64){
        float contrib = 0.f;
        if (t < 128){
            float wl = bfu(wlo[t]), wr = bfu(wro[t]);
            hwl[t] = f2bf(s_sc[t] * wl);
            hwr[t] = f2bf(s_sc[t] * wr);
            contrib = s_sh[t] * (wl + wr);
        }
        s_red[t] = contrib;
        __syncthreads();
        for (int off = 128; off >= 1; off >>= 1){
            if (t < off) s_red[t] += s_red[t + off];
            __syncthreads();
        }
        if (t == 0) hb[0] = s_red[0] + bfu(bo[0]);
    }
}

// ---- output head: y = h@Wl', r = h@Wr' (wave per node) ----
__global__ void __launch_bounds__(256) k_dot(const u16* h, const u16* wl, const u16* wr,
                                             float* y, float* r){
    int node = (blockIdx.x * 256 + threadIdx.x) >> 6;
    int lane = threadIdx.x & 63;
    if (node >= GN) return;
    u32 hv  = ((const u32*)h)[node * 64 + lane];
    u32 wlv = ((const u32*)wl)[lane];
    u32 wrv = ((const u32*)wr)[lane];
    float hlo = bl(hv), hhi = bh(hv);
    float ya = hlo * bl(wlv) + hhi * bh(wlv);
    float ra = hlo * bl(wrv) + hhi * bh(wrv);
    #pragma unroll
    for (int m = 1; m < 64; m <<= 1){ ya += __shfl_xor(ya, m); ra += __shfl_xor(ra, m); }
    if (lane == 0){ y[node] = ya; r[node] = ra; }
}

__global__ void __launch_bounds__(256) k_out(const float* y, const float* r, const int* deg,
                                             const int* col, const float* hb,
                                             const int* flags, void* out){
    int n = blockIdx.x * 256 + threadIdx.x;
    if (n >= GN) return;
    int d = deg[n];
    int cnt = d < DCAP ? d : DCAP;
    const int* nb = col + n * DCAP;
    float s = 0.f;
    for (int e = 0; e < cnt; ++e) s += y[nb[e]];
    float inv = (d > 0) ? 1.f / (float)d : 0.f;
    float z = inv * s + r[n] + hb[0];
    float sg = 1.f / (1.f + __expf(-z));
    if (flags[1]) ((float*)out)[n] = sg;
    else          ((u16*)out)[n] = f2bf(sg);
}

extern "C" void kernel_launch(void* const* d_in, const int* in_sizes, int n_in,
                              void* d_out, int out_size, void* d_ws, size_t ws_size,
                              hipStream_t stream) {
    const void* x     = d_in[0];
    const int*  ei    = (const int*)d_in[1];
    const void* Wl    = d_in[2];
    const void* Wr    = d_in[3];
    const void* bias  = d_in[4];
    const void* gamma = d_in[5];
    const void* beta  = d_in[6];
    const void* wlout = d_in[7];
    const void* wrout = d_in[8];
    const void* bout  = d_in[9];

    char* p = (char*)d_ws;
    auto take = [&](size_t b){ void* q = (void*)p; p += (b + 255) & ~(size_t)255; return q; };
    int*   cursor = (int*)  take((size_t)GN * 4);        // becomes deg after fillB
    int*   flags  = (int*)  take(256);
    int*   bcur   = (int*)  take((size_t)NBKT * 4);
    float* colpart= (float*)take(6144 * 4);              // per-layer [3][2048]
    float* biasf  = (float*)take(384 * 4);
    float* bf2    = (float*)take(128 * 4);
    float* bf3    = (float*)take(128 * 4);
    float* hb     = (float*)take(256);
    u16*   wf2    = (u16*)  take(32768 * 2);             // folded W layer 1
    u16*   wf3    = (u16*)  take(32768 * 2);             // folded W layer 2
    u16*   hwl    = (u16*)  take(128 * 2);
    u16*   hwr    = (u16*)  take(128 * 2);
    float* yv     = (float*)take((size_t)GN * 4);
    float* rv     = (float*)take((size_t)GN * 4);
    int*   col    = (int*)  take((size_t)GN * DCAP * 4); // padded CSR, 25.6 MB
    u16*   xb     = (u16*)  take((size_t)GN * 128 * 2);
    u16*   amean  = (u16*)  take((size_t)GN * 128 * 2);
    u16*   hbuf   = (u16*)  take((size_t)GN * 128 * 2);
    u32*   h8     = (u32*)  take((size_t)GN * 128);      // fp8 shadow, 12.8 MB
    u16*   wbuf   = (u16*)  take((size_t)WTOT * 2);

    // overlay: bucket pairs live in amean (19.3 MB <= 25.6 MB); dead before agg.
    u64* pairs = (u64*)amean;

    const int NB_N = (GN + 255) / 256;          // 391
    const int NB_A4 = (GN + 3) / 4;             // 25000 (one wave per block)
    const int NB_W = (GN + 3) / 4;              // 25000 (k_dot)
    const int NB_G = (GN + 127) / 128;          // 782
    const int NB_M = (GN * 16 + 255) / 256;     // 6250
    const int NB_C = (WTOT + 255) / 256;        // 390
    const int NB_A = (GE + 1023) / 1024;        // 1563

    k_init <<<NB_N, 256, 0, stream>>>(ei, (const u32*)x, cursor, colpart, flags, bcur);
    k_convx<<<NB_M, 256, 0, stream>>>(x, flags, xb, h8);
    k_convw<<<NB_C, 256, 0, stream>>>(Wl, Wr, bias, gamma, beta, wlout, wrout, bout, flags, wbuf, biasf);
    k_fillA<<<NB_A, 256, 0, stream>>>(ei, flags, bcur, pairs);
    k_fillB<<<1600, 256, 0, stream>>>(bcur, pairs, cursor, col);

    const u16* hin = xb;
    for (int i = 0; i < 3; ++i){
        const u16* Wlp; const u16* Wrp; const float* bfi;
        if (i == 0){ Wlp = wbuf;     Wrp = wbuf + WOFF_WR; bfi = biasf; }
        else if (i == 1){ Wlp = wf2; Wrp = wf2 + 16384;    bfi = bf2; }
        else { Wlp = wf3;            Wrp = wf3 + 16384;    bfi = bf3; }
        u16* wfd = (i == 0) ? wf2 : wf3;
        float* bNdst = (i == 0) ? bf2 : bf3;
        int nx = (i < 2) ? (i + 1) : 0;          // dummy for last layer
        k_agg <<<NB_A4, 64, 0, stream>>>(h8, cursor, col, amean);
        k_gemm<<<NB_G, 256, 0, stream>>>(amean, hin, Wlp, Wrp, bfi, hbuf,
                                         colpart + i * 2048);
        k_bnf <<<65, 256, 0, stream>>>(colpart + i * 2048,
            wbuf + WOFF_G + i * 128, wbuf + WOFF_BE + i * 128, (i == 2) ? 1 : 0,
            wbuf + nx * 16384, wbuf + WOFF_WR + nx * 16384, wfd,
            biasf + nx * 128, bNdst,
            wbuf + WOFF_WLO, wbuf + WOFF_WRO, wbuf + WOFF_BO, hwl, hwr, hb);
        if (i < 2) k_tofp8<<<NB_M, 256, 0, stream>>>(hbuf, h8);
        hin = hbuf;
    }
    k_dot<<<NB_W, 256, 0, stream>>>(hbuf, hwl, hwr, yv, rv);
    k_out<<<NB_N, 256, 0, stream>>>(yv, rv, cursor, col, hb, flags, d_out);
}

// Round 15
// 448.603 us; speedup vs baseline: 1.0309x; 1.0309x over previous
//
#include <hip/hip_runtime.h>

typedef unsigned short u16;
typedef unsigned int u32;
typedef unsigned long long u64;

#define GN 100000
#define GE 1600000
#define DCAP 64        // padded CSR capacity per node (Poisson(16); P(>64) ~ 1e-20)
#define NRANGE 196     // 512-node dst ranges
#define NBKT (NRANGE * 8)
#define BCAP 1536      // per-bucket capacity (mean ~1027, +16 sigma)

typedef __bf16 bf16x8 __attribute__((ext_vector_type(8)));
typedef float f32x4 __attribute__((ext_vector_type(4)));
typedef float f32x2 __attribute__((ext_vector_type(2)));
typedef u32 u32x4 __attribute__((ext_vector_type(4)));
typedef u32 u32x2 __attribute__((ext_vector_type(2)));

__device__ __forceinline__ float bl(u32 u){ return __uint_as_float(u << 16); }
__device__ __forceinline__ float bh(u32 u){ return __uint_as_float(u & 0xffff0000u); }
__device__ __forceinline__ float bfu(u16 v){ return __uint_as_float(((u32)v) << 16); }
__device__ __forceinline__ u16 f2bf(float f){
    u32 u = __float_as_uint(f);
    u32 r = (u + 0x7fffu + ((u >> 16) & 1u)) >> 16;
    return (u16)r;
}
__device__ __forceinline__ u32 pack2(float a, float b){
    return (u32)f2bf(a) | ((u32)f2bf(b) << 16);
}
// 4 floats -> 4 fp8 e4m3 (HW cvt, RNE)
__device__ __forceinline__ u32 pk8x4(float a, float b, float c, float d){
    u32 p = (u32)__builtin_amdgcn_cvt_pk_fp8_f32(a, b, 0, false);
    p = (u32)__builtin_amdgcn_cvt_pk_fp8_f32(c, d, p, true);
    return p;
}

// ---- init: zero cursor/colpart(3 layers)/bcur; detect dtypes ----
// flags[0]: 1 => edge_index int64; flags[1]: 1 => float tensors are f32
__global__ void __launch_bounds__(256) k_init(const int* ei, const u32* xraw,
                                              int* cursor, float* colpart, int* flags,
                                              int* bcur){
    int i = blockIdx.x * 256 + threadIdx.x;
    if (i < GN) cursor[i] = 0;
    if (i < NBKT) bcur[i] = 0;
    if (i < 6144) colpart[i] = 0.f;
    int t = threadIdx.x;
    if (blockIdx.x == 0){
        __shared__ int s_any[4];
        int v = 0;
        #pragma unroll
        for (int j = 0; j < 4; ++j){
            int k = t * 4 + j;                // k in [0,1024)
            v |= ei[2 * k * 1000 + 1];        // dword pos <= 2046001 < 3.2M
        }
        #pragma unroll
        for (int m = 1; m < 64; m <<= 1) v |= __shfl_xor(v, m);
        if ((t & 63) == 0) s_any[t >> 6] = v;
        __syncthreads();
        if (t == 0){
            int any = s_any[0] | s_any[1] | s_any[2] | s_any[3];
            flags[0] = (any == 0) ? 1 : 0;
        }
    }
    if (blockIdx.x == 1){
        __shared__ int s_cnt[4];
        // low u16 of each dword: bf16 of ~N(0,1) has exponent in [100,140];
        // f32 mantissa bits hit that window ~16% of the time.
        int cnt = 0;
        #pragma unroll
        for (int j = 0; j < 4; ++j){
            int idx = (t * 4 + j) * 6000 + 3;     // < 6.15M dwords, safe both ways
            u32 u = xraw[idx];
            int e = (u >> 7) & 0xFF;
            cnt += (e >= 100 && e <= 140) ? 1 : 0;
        }
        #pragma unroll
        for (int m = 1; m < 64; m <<= 1) cnt += __shfl_xor(cnt, m);
        if ((t & 63) == 0) s_cnt[t >> 6] = cnt;
        __syncthreads();
        if (t == 0){
            int tot = s_cnt[0] + s_cnt[1] + s_cnt[2] + s_cnt[3];
            flags[1] = (tot > 512) ? 0 : 1;
        }
    }
}

// ---- convert x -> internal bf16 + fp8 shadow copy for the gather ----
__global__ void __launch_bounds__(256) k_convx(const void* x, const int* flags,
                                               u16* xb, u32* h8){
    int gid = blockIdx.x * 256 + threadIdx.x;     // one 8-element chunk
    if (gid >= GN * 16) return;
    float f0,f1,f2,f3,f4,f5,f6,f7;
    if (flags[1]){
        const u32x4* xf = (const u32x4*)x;
        u32x4 a = __builtin_nontemporal_load(xf + gid * 2);
        u32x4 b = __builtin_nontemporal_load(xf + gid * 2 + 1);
        f0 = __uint_as_float(a.x); f1 = __uint_as_float(a.y);
        f2 = __uint_as_float(a.z); f3 = __uint_as_float(a.w);
        f4 = __uint_as_float(b.x); f5 = __uint_as_float(b.y);
        f6 = __uint_as_float(b.z); f7 = __uint_as_float(b.w);
    } else {
        u32x4 g = __builtin_nontemporal_load((const u32x4*)x + gid);
        f0 = bl(g.x); f1 = bh(g.x); f2 = bl(g.y); f3 = bh(g.y);
        f4 = bl(g.z); f5 = bh(g.z); f6 = bl(g.w); f7 = bh(g.w);
    }
    u32x4 o;
    o.x = pack2(f0, f1); o.y = pack2(f2, f3);
    o.z = pack2(f4, f5); o.w = pack2(f6, f7);
    ((u32x4*)xb)[gid] = o;
    u32x2 e = { pk8x4(f0, f1, f2, f3), pk8x4(f4, f5, f6, f7) };
    ((u32x2*)h8)[gid] = e;
}

// ---- bf16 h -> fp8 shadow copy (refresh h8 between layers; clean seq writes) ----
__global__ void __launch_bounds__(256) k_tofp8(const u16* h, u32* h8){
    int gid = blockIdx.x * 256 + threadIdx.x;     // one 8-element chunk
    if (gid >= GN * 16) return;
    u32x4 g = ((const u32x4*)h)[gid];
    u32x2 e = { pk8x4(bl(g.x), bh(g.x), bl(g.y), bh(g.y)),
                pk8x4(bl(g.z), bh(g.z), bl(g.w), bh(g.w)) };
    ((u32x2*)h8)[gid] = e;
}

// ---- convert params -> bf16 block; Wl/Wr regions in GRANULE layout ----
// granule j (8 u16) = W[k=(j>>7)*8 .. +7][c=j&127] (8 consecutive k, fixed col)
#define WOFF_WR    49152
#define WOFF_B     98304
#define WOFF_G     98688
#define WOFF_BE    99072
#define WOFF_WLO   99456
#define WOFF_WRO   99584
#define WOFF_BO    99712
#define WTOT       99713
__global__ void __launch_bounds__(256) k_convw(const void* Wl, const void* Wr, const void* b,
                                               const void* g, const void* be, const void* wlo,
                                               const void* wro, const void* bo,
                                               const int* flags, u16* wbuf, float* biasf){
    int i = blockIdx.x * 256 + threadIdx.x;
    if (i >= WTOT) return;
    const void* s; int k;
    if (i < WOFF_B){
        const void* src = (i < WOFF_WR) ? Wl : Wr;
        int r = (i < WOFF_WR) ? i : i - WOFF_WR;
        int layer = r >> 14, L = r & 16383;
        int kk = ((L >> 10) << 3) | (L & 7);
        int cc = (L >> 3) & 127;
        int si = layer * 16384 + kk * 128 + cc;
        float fv = flags[1] ? ((const float*)src)[si] : bfu(((const u16*)src)[si]);
        wbuf[i] = f2bf(fv);
        return;
    }
    if      (i < WOFF_G  ){ s = b;   k = i - WOFF_B; }
    else if (i < WOFF_BE ){ s = g;   k = i - WOFF_G; }
    else if (i < WOFF_WLO){ s = be;  k = i - WOFF_BE; }
    else if (i < WOFF_WRO){ s = wlo; k = i - WOFF_WLO; }
    else if (i < WOFF_BO ){ s = wro; k = i - WOFF_WRO; }
    else                  { s = bo;  k = 0; }
    float fv = flags[1] ? ((const float*)s)[k] : bfu(((const u16*)s)[k]);
    wbuf[i] = f2bf(fv);
    if (i >= WOFF_B && i < WOFF_B + 384) biasf[i - WOFF_B] = fv;
}

// ---- pass A: LDS-staged radix scatter; wave-level shfl scan (5 barriers) ----
__global__ void __launch_bounds__(256) k_fillA(const int* ei, const int* flags,
                                               int* bcur, u64* pairs){
    __shared__ int cnt[256];
    __shared__ int lofs[256];
    __shared__ int gbase[NRANGE];
    __shared__ int wsum[4];
    __shared__ u64 lp[1024];
    int t = threadIdx.x;
    int lane = t & 63, w = t >> 6;
    int res = blockIdx.x & 7;
    int base = blockIdx.x * 1024;
    int is64 = flags[0];
    cnt[t] = 0;
    __syncthreads();
    int myd[4], mys[4], slot[4], myr[4];
    #pragma unroll
    for (int j = 0; j < 4; ++j){
        int e = base + j * 256 + t;
        if (e < GE){
            int d, s;
            if (is64){ d = __builtin_nontemporal_load(ei + 2 * (GE + e));
                       s = __builtin_nontemporal_load(ei + 2 * e); }
            else     { d = __builtin_nontemporal_load(ei + GE + e);
                       s = __builtin_nontemporal_load(ei + e); }
            myd[j] = d; mys[j] = s; myr[j] = d >> 9;
            slot[j] = atomicAdd(&cnt[myr[j]], 1);
        } else myr[j] = -1;
    }
    __syncthreads();
    int v = cnt[t];
    int sv = v;
    #pragma unroll
    for (int d = 1; d < 64; d <<= 1){
        int u = __shfl_up(sv, d);
        if (lane >= d) sv += u;
    }
    if (lane == 63) wsum[w] = sv;
    __syncthreads();
    int prefix = 0;
    #pragma unroll
    for (int j = 0; j < 4; ++j) if (j < w) prefix += wsum[j];
    lofs[t] = sv + prefix - v;                                  // exclusive
    if (t < NRANGE && cnt[t] > 0)
        gbase[t] = atomicAdd(&bcur[t * 8 + res], cnt[t]);
    __syncthreads();
    #pragma unroll
    for (int j = 0; j < 4; ++j){
        if (myr[j] >= 0)
            lp[lofs[myr[j]] + slot[j]] = ((u64)(u32)myd[j] << 32) | (u32)mys[j];
    }
    __syncthreads();
    int total = GE - base; if (total > 1024) total = 1024;
    for (int i = t; i < total; i += 256){
        u64 pr = lp[i];
        int r = (int)(pr >> 32) >> 9;
        int g = gbase[r] + (i - lofs[r]);
        if (g < BCAP) pairs[((size_t)(r * 8 + res)) * BCAP + g] = pr;
    }
}

// ---- pass B: scatter buckets into padded CSR (b%8 == range%8 => one XCD/window) ----
__global__ void __launch_bounds__(256) k_fillB(const int* bcur, const u64* pairs,
                                               int* cursor, int* col){
    int range = blockIdx.x % 200;
    int sub   = blockIdx.x / 200;
    if (range >= NRANGE || sub >= 8) return;
    int bkt = range * 8 + sub;
    int n = bcur[bkt]; if (n > BCAP) n = BCAP;
    const u64* P = pairs + (size_t)bkt * BCAP;
    for (int i = threadIdx.x; i < n; i += 256){
        u64 pr = __builtin_nontemporal_load(P + i);
        int s = (int)(u32)pr, d = (int)(pr >> 32);
        int pos = atomicAdd(&cursor[d], 1);
        if (pos < DCAP) col[d * DCAP + pos] = s;
    }
}

// ---- mean aggregation over the fp8 shadow: one wave (4 nodes), u32x2/lane,
// HW cvt decode, PACKED f32 accumulate (v_pk_add_f32: 4 cvt + 4 pk-adds per
// 8 features vs 4+8 scalar), bf16 out. Row = 128 B = 2 cache lines.
__global__ void __launch_bounds__(64) k_agg(const u32* h8, const int* deg, const int* col,
                                            u16* amean){
    int lane = threadIdx.x;
    int grp = lane >> 4;                 // node within wave (0..3)
    int lg  = lane & 15;                 // 8B granule index within row
    int node = blockIdx.x * 4 + grp;
    if (node >= GN) return;
    int d = deg[node];
    int cnt = d < DCAP ? d : DCAP;
    const int* nb = col + node * DCAP;
    const u32x2* hrow = (const u32x2*)h8;      // 16 granules per 128-feat row
    f32x2 A01 = {0.f, 0.f}, A23 = {0.f, 0.f}, A45 = {0.f, 0.f}, A67 = {0.f, 0.f};
    int e = 0;
    #define ACC8(v) { \
        A01 += __builtin_amdgcn_cvt_pk_f32_fp8((v).x, false); \
        A23 += __builtin_amdgcn_cvt_pk_f32_fp8((v).x, true);  \
        A45 += __builtin_amdgcn_cvt_pk_f32_fp8((v).y, false); \
        A67 += __builtin_amdgcn_cvt_pk_f32_fp8((v).y, true); }
    for (; e + 7 < cnt; e += 8){
        u32x2 v0 = hrow[(size_t)nb[e]     * 16 + lg];
        u32x2 v1 = hrow[(size_t)nb[e + 1] * 16 + lg];
        u32x2 v2 = hrow[(size_t)nb[e + 2] * 16 + lg];
        u32x2 v3 = hrow[(size_t)nb[e + 3] * 16 + lg];
        u32x2 v4 = hrow[(size_t)nb[e + 4] * 16 + lg];
        u32x2 v5 = hrow[(size_t)nb[e + 5] * 16 + lg];
        u32x2 v6 = hrow[(size_t)nb[e + 6] * 16 + lg];
        u32x2 v7 = hrow[(size_t)nb[e + 7] * 16 + lg];
        ACC8(v0) ACC8(v1) ACC8(v2) ACC8(v3) ACC8(v4) ACC8(v5) ACC8(v6) ACC8(v7)
    }
    for (; e + 1 < cnt; e += 2){
        u32x2 v0 = hrow[(size_t)nb[e]     * 16 + lg];
        u32x2 v1 = hrow[(size_t)nb[e + 1] * 16 + lg];
        ACC8(v0) ACC8(v1)
    }
    if (e < cnt){
        u32x2 v0 = hrow[(size_t)nb[e] * 16 + lg];
        ACC8(v0)
    }
    #undef ACC8
    float inv = (d > 0) ? 1.f / (float)d : 0.f;
    f32x2 iv = {inv, inv};
    A01 *= iv; A23 *= iv; A45 *= iv; A67 *= iv;
    u32x4 o;
    o.x = pack2(A01.x, A01.y);
    o.y = pack2(A23.x, A23.y);
    o.z = pack2(A45.x, A45.y);
    o.w = pack2(A67.x, A67.y);
    ((u32x4*)amean)[(size_t)node * 16 + lg] = o;
}

// ---- BARRIER-FREE GEMM: hout = relu([amean|hin]@[Wl;Wr]+b).
// W is PRE-FOLDED (BN scale baked by k_bnf) in global granule layout and read
// per-fragment straight from L2 (64KB working set, hot in every XCD L2) —
// no LDS staging, no staging barriers. LDS = 1KB stats buffer only.
__global__ void __launch_bounds__(256, 4) k_gemm(const u16* amean, const u16* hin,
                                                 const u16* Wlp, const u16* Wrp,
                                                 const float* biasf,
                                                 u16* hout, float* colpart){
    __shared__ float sst[256];        // sum[128], sumsq[128]
    int t = threadIdx.x;
    int wid = t >> 6, lane = t & 63;
    int quad = lane >> 4, l15 = lane & 15;
    int r0 = blockIdx.x * 128 + wid * 32;
    int node0 = r0 + l15, node1 = r0 + 16 + l15;
    sst[t] = 0.f;

    f32x4 acc[2][8];
    #pragma unroll
    for (int i = 0; i < 2; i++)
        #pragma unroll
        for (int j = 0; j < 8; j++) acc[i][j] = (f32x4){0.f, 0.f, 0.f, 0.f};

    #pragma unroll
    for (int half = 0; half < 2; ++half){
        const u16* A = half ? hin : amean;
        const u32x4* Wg = (const u32x4*)(half ? Wrp : Wlp);
        #pragma unroll
        for (int s = 0; s < 4; ++s){
            int kk = (s << 5) + (quad << 3);
            union { u32x4 u; bf16x8 v; } fa0, fa1;
            fa0.u = (node0 < GN) ? *(const u32x4*)(A + node0 * 128 + kk) : (u32x4){0,0,0,0};
            fa1.u = (node1 < GN) ? *(const u32x4*)(A + node1 * 128 + kk) : (u32x4){0,0,0,0};
            int kc = (s << 2) + quad;        // k-octet 0..15 within this half
            const u32x4* wg = Wg + (kc << 7) + l15;
            #pragma unroll
            for (int cb = 0; cb < 8; ++cb){
                union { u32x4 u; bf16x8 v; } fw;
                fw.u = wg[cb << 4];          // granule = kc*128 + cb*16 + l15
                acc[0][cb] = __builtin_amdgcn_mfma_f32_16x16x32_bf16(fa0.v, fw.v, acc[0][cb], 0, 0, 0);
                acc[1][cb] = __builtin_amdgcn_mfma_f32_16x16x32_bf16(fa1.v, fw.v, acc[1][cb], 0, 0, 0);
            }
        }
    }
    __syncthreads();                  // sst zero-init visible to all

    float bsv[8];
    #pragma unroll
    for (int cb = 0; cb < 8; cb++) bsv[cb] = biasf[cb * 16 + l15];

    #pragma unroll
    for (int cb = 0; cb < 8; cb++){
        float csum = 0.f, csq = 0.f;
        #pragma unroll
        for (int rb = 0; rb < 2; rb++){
            int rbase = r0 + rb * 16 + quad * 4;
            #pragma unroll
            for (int rr = 0; rr < 4; rr++){
                int row = rbase + rr;
                float v = acc[rb][cb][rr] + bsv[cb];
                v = fmaxf(v, 0.f);
                if (row < GN) hout[row * 128 + cb * 16 + l15] = f2bf(v);
                float vm = (row < GN) ? v : 0.f;
                csum += vm; csq += vm * vm;
            }
        }
        csum += __shfl_xor(csum, 16); csum += __shfl_xor(csum, 32);
        csq  += __shfl_xor(csq, 16);  csq  += __shfl_xor(csq, 32);
        if (quad == 0){
            atomicAdd(&sst[cb * 16 + l15], csum);
            atomicAdd(&sst[128 + cb * 16 + l15], csq);
        }
    }
    __syncthreads();
    atomicAdd(&colpart[(blockIdx.x & 7) * 256 + t], sst[t]);
}

// ---- BN finalize + fold: blocks 0..63 write next layer's scaled W (granule),
// block 64 folds bias (mode 0) or the output head (mode 1). ----
__global__ void __launch_bounds__(256) k_bnf(const float* colpart, const u16* gamma, const u16* beta,
                                             int mode,
                                             const u16* WlN, const u16* WrN, u16* wfd,
                                             const float* bNsrc, float* bNdst,
                                             const u16* wlo, const u16* wro, const u16* bo,
                                             u16* hwl, u16* hwr, float* hb){
    __shared__ float s_sc[128], s_sh[128], s_red[256];
    int t = threadIdx.x, b = blockIdx.x;
    if (t < 128){
        float s = 0.f, q = 0.f;
        #pragma unroll
        for (int j = 0; j < 8; ++j){
            s += colpart[j * 256 + t];
            q += colpart[j * 256 + 128 + t];
        }
        const float invn = 1.f / (float)GN;
        float mean = s * invn;
        float var = fmaxf(q * invn - mean * mean, 0.f);
        float rstd = rsqrtf(var + 1e-5f);
        float g  = bfu(gamma[t]);
        float be = bfu(beta[t]);
        float sc = g * rstd, sh = be - mean * sc;
        s_sc[t] = sc; s_sh[t] = sh;
    }
    __syncthreads();
    if (mode == 0){
        if (b < 64){
            int idx = b * 256 + t;            // granule index 0..16383
            int k = ((idx >> 10) << 3) | (idx & 7);
            float sc = s_sc[k];
            wfd[idx]         = f2bf(sc * bfu(WlN[idx]));
            wfd[16384 + idx] = f2bf(sc * bfu(WrN[idx]));
        } else if (t < 128){
            float acc = bNsrc[t];
            for (int k = 0; k < 128; ++k){
                int L = ((k >> 3) << 10) + (t << 3) + (k & 7);   // granule layout
                acc += s_sh[k] * (bfu(WlN[L]) + bfu(WrN[L]));
            }
            bNdst[t] = acc;
        }
    } else if (b == 64){
        float contrib = 0.f;
        if (t < 128){
            float wl = bfu(wlo[t]), wr = bfu(wro[t]);
            hwl[t] = f2bf(s_sc[t] * wl);
            hwr[t] = f2bf(s_sc[t] * wr);
            contrib = s_sh[t] * (wl + wr);
        }
        s_red[t] = contrib;
        __syncthreads();
        for (int off = 128; off >= 1; off >>= 1){
            if (t < off) s_red[t] += s_red[t + off];
            __syncthreads();
        }
        if (t == 0) hb[0] = s_red[0] + bfu(bo[0]);
    }
}

// ---- output head: y = h@Wl', r = h@Wr' (wave per node) ----
__global__ void __launch_bounds__(256) k_dot(const u16* h, const u16* wl, const u16* wr,
                                             float* y, float* r){
    int node = (blockIdx.x * 256 + threadIdx.x) >> 6;
    int lane = threadIdx.x & 63;
    if (node >= GN) return;
    u32 hv  = ((const u32*)h)[node * 64 + lane];
    u32 wlv = ((const u32*)wl)[lane];
    u32 wrv = ((const u32*)wr)[lane];
    float hlo = bl(hv), hhi = bh(hv);
    float ya = hlo * bl(wlv) + hhi * bh(wlv);
    float ra = hlo * bl(wrv) + hhi * bh(wrv);
    #pragma unroll
    for (int m = 1; m < 64; m <<= 1){ ya += __shfl_xor(ya, m); ra += __shfl_xor(ra, m); }
    if (lane == 0){ y[node] = ya; r[node] = ra; }
}

__global__ void __launch_bounds__(256) k_out(const float* y, const float* r, const int* deg,
                                             const int* col, const float* hb,
                                             const int* flags, void* out){
    int n = blockIdx.x * 256 + threadIdx.x;
    if (n >= GN) return;
    int d = deg[n];
    int cnt = d < DCAP ? d : DCAP;
    const int* nb = col + n * DCAP;
    float s = 0.f;
    for (int e = 0; e < cnt; ++e) s += y[nb[e]];
    float inv = (d > 0) ? 1.f / (float)d : 0.f;
    float z = inv * s + r[n] + hb[0];
    float sg = 1.f / (1.f + __expf(-z));
    if (flags[1]) ((float*)out)[n] = sg;
    else          ((u16*)out)[n] = f2bf(sg);
}

extern "C" void kernel_launch(void* const* d_in, const int* in_sizes, int n_in,
                              void* d_out, int out_size, void* d_ws, size_t ws_size,
                              hipStream_t stream) {
    const void* x     = d_in[0];
    const int*  ei    = (const int*)d_in[1];
    const void* Wl    = d_in[2];
    const void* Wr    = d_in[3];
    const void* bias  = d_in[4];
    const void* gamma = d_in[5];
    const void* beta  = d_in[6];
    const void* wlout = d_in[7];
    const void* wrout = d_in[8];
    const void* bout  = d_in[9];

    char* p = (char*)d_ws;
    auto take = [&](size_t b){ void* q = (void*)p; p += (b + 255) & ~(size_t)255; return q; };
    int*   cursor = (int*)  take((size_t)GN * 4);        // becomes deg after fillB
    int*   flags  = (int*)  take(256);
    int*   bcur   = (int*)  take((size_t)NBKT * 4);
    float* colpart= (float*)take(6144 * 4);              // per-layer [3][2048]
    float* biasf  = (float*)take(384 * 4);
    float* bf2    = (float*)take(128 * 4);
    float* bf3    = (float*)take(128 * 4);
    float* hb     = (float*)take(256);
    u16*   wf2    = (u16*)  take(32768 * 2);             // folded W layer 1
    u16*   wf3    = (u16*)  take(32768 * 2);             // folded W layer 2
    u16*   hwl    = (u16*)  take(128 * 2);
    u16*   hwr    = (u16*)  take(128 * 2);
    float* yv     = (float*)take((size_t)GN * 4);
    float* rv     = (float*)take((size_t)GN * 4);
    int*   col    = (int*)  take((size_t)GN * DCAP * 4); // padded CSR, 25.6 MB
    u16*   xb     = (u16*)  take((size_t)GN * 128 * 2);
    u16*   amean  = (u16*)  take((size_t)GN * 128 * 2);
    u16*   hbuf   = (u16*)  take((size_t)GN * 128 * 2);
    u32*   h8     = (u32*)  take((size_t)GN * 128);      // fp8 shadow, 12.8 MB
    u16*   wbuf   = (u16*)  take((size_t)WTOT * 2);

    // overlay: bucket pairs live in amean (19.3 MB <= 25.6 MB); dead before agg.
    u64* pairs = (u64*)amean;

    const int NB_N = (GN + 255) / 256;          // 391
    const int NB_A4 = (GN + 3) / 4;             // 25000 (one wave per block)
    const int NB_W = (GN + 3) / 4;              // 25000 (k_dot)
    const int NB_G = (GN + 127) / 128;          // 782
    const int NB_M = (GN * 16 + 255) / 256;     // 6250
    const int NB_C = (WTOT + 255) / 256;        // 390
    const int NB_A = (GE + 1023) / 1024;        // 1563

    k_init <<<NB_N, 256, 0, stream>>>(ei, (const u32*)x, cursor, colpart, flags, bcur);
    k_convx<<<NB_M, 256, 0, stream>>>(x, flags, xb, h8);
    k_convw<<<NB_C, 256, 0, stream>>>(Wl, Wr, bias, gamma, beta, wlout, wrout, bout, flags, wbuf, biasf);
    k_fillA<<<NB_A, 256, 0, stream>>>(ei, flags, bcur, pairs);
    k_fillB<<<1600, 256, 0, stream>>>(bcur, pairs, cursor, col);

    const u16* hin = xb;
    for (int i = 0; i < 3; ++i){
        const u16* Wlp; const u16* Wrp; const float* bfi;
        if (i == 0){ Wlp = wbuf;     Wrp = wbuf + WOFF_WR; bfi = biasf; }
        else if (i == 1){ Wlp = wf2; Wrp = wf2 + 16384;    bfi = bf2; }
        else { Wlp = wf3;            Wrp = wf3 + 16384;    bfi = bf3; }
        u16* wfd = (i == 0) ? wf2 : wf3;
        float* bNdst = (i == 0) ? bf2 : bf3;
        int nx = (i < 2) ? (i + 1) : 0;          // dummy for last layer
        k_agg <<<NB_A4, 64, 0, stream>>>(h8, cursor, col, amean);
        k_gemm<<<NB_G, 256, 0, stream>>>(amean, hin, Wlp, Wrp, bfi, hbuf,
                                         colpart + i * 2048);
        k_bnf <<<65, 256, 0, stream>>>(colpart + i * 2048,
            wbuf + WOFF_G + i * 128, wbuf + WOFF_BE + i * 128, (i == 2) ? 1 : 0,
            wbuf + nx * 16384, wbuf + WOFF_WR + nx * 16384, wfd,
            biasf + nx * 128, bNdst,
            wbuf + WOFF_WLO, wbuf + WOFF_WRO, wbuf + WOFF_BO, hwl, hwr, hb);
        if (i < 2) k_tofp8<<<NB_M, 256, 0, stream>>>(hbuf, h8);
        hin = hbuf;
    }
    k_dot<<<NB_W, 256, 0, stream>>>(hbuf, hwl, hwr, yv, rv);
    k_out<<<NB_N, 256, 0, stream>>>(yv, rv, cursor, col, hb, flags, d_out);
}